// Round 1
// baseline (91.637 us; speedup 1.0000x reference)
//
#include <hip/hip_runtime.h>

#define BATCH 8
#define NPTS 9225
#define MQ 4096
#define CAP 64
#define GRID 64
#define NCELLS (GRID * GRID)   // 4096; window = cx±2, cy±2 (5x5 cells)
#define TOTPTS (BATCH * NPTS)  // 73800
// coverage margin: query at qx covers [ (cx-2)/64, (cx+3)/64 ) => >= 2/64 =
// 0.03125 each side vs r = 0.03 (+fp32-expansion slack ~2e-6).

__device__ __forceinline__ int cell_of(float x, float y) {
  int cx = (int)(x * (float)GRID);
  int cy = (int)(y * (float)GRID);
  cx = min(max(cx, 0), GRID - 1);
  cy = min(max(cy, 0), GRID - 1);
  return cy * GRID + cx;
}

// ---- build stage, re-parallelized (R6): the old single-block-per-batch
// build serialized ~18.5K LDS atomics on 8 CUs (3% of machine) while 8192
// search blocks waited. Now: wide global-atomic hist + wide scatter; only
// the cheap scan stays at 8 blocks. ----

__global__ __launch_bounds__(1024) void zero_hist_kernel(int* __restrict__ hist) {
  hist[blockIdx.x * 1024 + threadIdx.x] = 0;  // grid sized exactly: 32*1024
}

__global__ __launch_bounds__(256) void hist_kernel(
    const float* __restrict__ data, int* __restrict__ hist) {
  const int f = blockIdx.x * 256 + threadIdx.x;
  if (f >= TOTPTS) return;
  const float2 p = ((const float2*)data)[f];
  const unsigned b = (unsigned)f / (unsigned)NPTS;  // magic-mul
  atomicAdd(&hist[b * NCELLS + cell_of(p.x, p.y)], 1);
}

// Per-batch exclusive scan of 4096 cell counts (same shfl scan as before,
// reading the global hist instead of LDS); writes cell_starts + cursor init.
__global__ __launch_bounds__(1024) void scan_cells_kernel(
    const int* __restrict__ hist,
    int* __restrict__ cell_starts,   // [B][NCELLS+1]
    int* __restrict__ cursor) {      // [B][NCELLS]
  __shared__ int wavesum[16];
  const int b = blockIdx.x;
  const int t = threadIdx.x;
  const int* h = hist + b * NCELLS;
  const int c0 = h[4 * t + 0], c1 = h[4 * t + 1];
  const int c2 = h[4 * t + 2], c3 = h[4 * t + 3];
  const int s = c0 + c1 + c2 + c3;
  const int lane = t & 63, wid = t >> 6;
  int v = s;
#pragma unroll
  for (int off = 1; off < 64; off <<= 1) {
    const int u = __shfl_up(v, off, 64);
    if (lane >= off) v += u;
  }
  if (lane == 63) wavesum[wid] = v;
  __syncthreads();
  int woff = 0;
  for (int k = 0; k < wid; ++k) woff += wavesum[k];
  int e = woff + v - s;  // exclusive prefix of cell 4t
  int* cs = cell_starts + b * (NCELLS + 1);
  int* cu = cursor + b * NCELLS;
  cs[4 * t + 0] = e; cu[4 * t + 0] = e; e += c0;
  cs[4 * t + 1] = e; cu[4 * t + 1] = e; e += c1;
  cs[4 * t + 2] = e; cu[4 * t + 2] = e; e += c2;
  cs[4 * t + 3] = e; cu[4 * t + 3] = e; e += c3;
  if (t == 1023) cs[NCELLS] = e;  // == NPTS
}

__global__ __launch_bounds__(256) void scatter_kernel(
    const float* __restrict__ data, int* __restrict__ cursor,
    float4* __restrict__ recs) {
  const int f = blockIdx.x * 256 + threadIdx.x;
  if (f >= TOTPTS) return;
  const float2 p = ((const float2*)data)[f];
  const unsigned b = (unsigned)f / (unsigned)NPTS;
  const int i = f - (int)b * NPTS;  // index within batch
  const int pos = atomicAdd(&cursor[b * NCELLS + cell_of(p.x, p.y)], 1);
  recs[(size_t)b * NPTS + pos] = make_float4(p.x, p.y, __int_as_float(i), 0.0f);
}

// One wave per query; 5 cell-rows concatenated into one lane-mapped stream,
// one 16B record load per candidate. UNCHANGED this round (isolate the
// build-stage variable).
__global__ __launch_bounds__(256) void search_kernel(
    const float* __restrict__ queries, const float* __restrict__ radius_p,
    const int* __restrict__ cell_starts, const float4* __restrict__ recs,
    int* __restrict__ nbr_idx, int* __restrict__ counts) {
#pragma clang fp contract(off)
  __shared__ int hitbuf[4][CAP];
  const int lane = threadIdx.x & 63;
  const int w = threadIdx.x >> 6;
  const int q = blockIdx.x * 4 + w;     // grid sized exactly
  const int b = q >> 12;                // MQ = 4096
  const float r = radius_p[0];
  const float r2 = r * r;
  const float2 qv = ((const float2*)queries)[q];
  const float qx = qv.x, qy = qv.y;
  const float qn = qx * qx + qy * qy;   // mul,mul,add — no fma (matches np)

  const int cx = min(max((int)(qx * (float)GRID), 0), GRID - 1);
  const int cy = min(max((int)(qy * (float)GRID), 0), GRID - 1);
  const int x0 = max(cx - 2, 0), x1 = min(cx + 2, GRID - 1);
  const int y0 = max(cy - 2, 0), y1 = min(cy + 2, GRID - 1);

  const int csbase = b * (NCELLS + 1);
  int rstart[5], rlen[5];
  int nr = 0;
  for (int y = y0; y <= y1; ++y) {      // wave-uniform trip count (3..5)
    const int s0 = cell_starts[csbase + y * GRID + x0];
    const int s1 = cell_starts[csbase + y * GRID + x1 + 1];
    rstart[nr] = s0;
    rlen[nr] = s1 - s0;
    ++nr;
  }
  for (int k = nr; k < 5; ++k) { rstart[k] = 0; rlen[k] = 0; }
  const int L0 = rlen[0];
  const int L1 = L0 + rlen[1];
  const int L2 = L1 + rlen[2];
  const int L3 = L2 + rlen[3];
  const int T = L3 + rlen[4];

  const unsigned long long below = (1ull << lane) - 1ull;
  const float4* rb = recs + (size_t)b * NPTS;
  int h = 0;

  for (int base = 0; base < T; base += 64) {
    const int p = base + lane;
    const bool act = (p < T);
    int i;
    if (p < L0)      i = rstart[0] + p;
    else if (p < L1) i = rstart[1] + (p - L0);
    else if (p < L2) i = rstart[2] + (p - L1);
    else if (p < L3) i = rstart[3] + (p - L2);
    else             i = rstart[4] + (p - L3);
    if (!act) i = 0;  // safe address
    const float4 rec = rb[i];
    const float dx = rec.x, dy = rec.y;
    const int id = __float_as_int(rec.z);
    const float dn = dx * dx + dy * dy;            // mul,mul,add — no fma
    const float cross = qx * dx + qy * dy;         // mul,mul,add — no fma
    const float s = (qn + dn) - 2.0f * cross;      // matches np op order
    const bool in = act && (s <= r2);
    const unsigned long long mask = __ballot(in);
    if (in) {
      const int pos = h + __popcll(mask & below);
      if (pos < CAP) hitbuf[w][pos] = id;
    }
    h += __popcll(mask);
  }

  // gather (same-wave LDS RAW is in-order)
  int v = (lane < h && lane < CAP) ? hitbuf[w][lane] : 0x7fffffff;

  // bitonic sort: k=2..32 sorts each 32-half (high half = all-MAX)
#pragma unroll
  for (int k = 2; k <= 32; k <<= 1) {
#pragma unroll
    for (int j = k >> 1; j >= 1; j >>= 1) {
      const int other = __shfl_xor(v, j, 64);
      const bool keep_min = (((lane & k) == 0) == ((lane & j) == 0));
      v = keep_min ? min(v, other) : max(v, other);
    }
  }
  if (h > 32) {  // final 64-merge only if hits spill past lane 31
#pragma unroll
    for (int j = 32; j >= 1; j >>= 1) {
      const int other = __shfl_xor(v, j, 64);
      const bool keep_min = ((lane & j) == 0);
      v = keep_min ? min(v, other) : max(v, other);
    }
  }

  nbr_idx[(size_t)q * CAP + lane] = (v == 0x7fffffff) ? -1 : v;
  if (lane == 0) counts[q] = h;
}

// Per-batch exclusive scan of 4096 counts -> row_splits[b][0..4096]
__global__ __launch_bounds__(256) void scan_kernel(const int* __restrict__ counts,
                                                   int* __restrict__ row_splits) {
  const int b = blockIdx.x;
  const int t = threadIdx.x;
  const int PER = MQ / 256;  // 16
  __shared__ int partial[256];
  const int* c = counts + b * MQ;
  int local[PER];
  int sum = 0;
#pragma unroll
  for (int k = 0; k < PER; ++k) { local[k] = c[t * PER + k]; sum += local[k]; }
  partial[t] = sum;
  __syncthreads();
  for (int off = 1; off < 256; off <<= 1) {
    int u = (t >= off) ? partial[t - off] : 0;
    __syncthreads();
    partial[t] += u;
    __syncthreads();
  }
  const int excl = (t == 0) ? 0 : partial[t - 1];
  int* rs = row_splits + b * (MQ + 1);
  if (t == 0) rs[0] = 0;
  int run = excl;
#pragma unroll
  for (int k = 0; k < PER; ++k) { run += local[k]; rs[t * PER + k + 1] = run; }
}

extern "C" void kernel_launch(void* const* d_in, const int* in_sizes, int n_in,
                              void* d_out, int out_size, void* d_ws, size_t ws_size,
                              hipStream_t stream) {
  const float* data    = (const float*)d_in[0];
  const float* queries = (const float*)d_in[1];
  const float* radius  = (const float*)d_in[2];
  int* out        = (int*)d_out;
  int* nbr_idx    = out;                       // BATCH*MQ*CAP
  int* row_splits = out + BATCH * MQ * CAP;    // BATCH*(MQ+1)

  // workspace layout (ints): counts[32768] + cell_starts[8*4097=32776] +
  // hist[32768] + cursor[32768] = 131080 ints = 524320 B, divisible by 16
  // -> recs is 16B-aligned.
  int* counts      = (int*)d_ws;                           // 32768
  int* cell_starts = counts + BATCH * MQ;                  // 32776
  int* hist        = cell_starts + BATCH * (NCELLS + 1);   // 32768
  int* cursor      = hist + BATCH * NCELLS;                // 32768
  float4* recs     = (float4*)(cursor + BATCH * NCELLS);

  const int PT_BLOCKS = (TOTPTS + 255) / 256;  // 289

  hipLaunchKernelGGL(zero_hist_kernel, dim3(BATCH * NCELLS / 1024), dim3(1024),
                     0, stream, hist);
  hipLaunchKernelGGL(hist_kernel, dim3(PT_BLOCKS), dim3(256), 0, stream,
                     data, hist);
  hipLaunchKernelGGL(scan_cells_kernel, dim3(BATCH), dim3(1024), 0, stream,
                     hist, cell_starts, cursor);
  hipLaunchKernelGGL(scatter_kernel, dim3(PT_BLOCKS), dim3(256), 0, stream,
                     data, cursor, recs);
  hipLaunchKernelGGL(search_kernel, dim3(BATCH * MQ / 4), dim3(256), 0, stream,
                     queries, radius, cell_starts, recs, nbr_idx, counts);
  hipLaunchKernelGGL(scan_kernel, dim3(BATCH), dim3(256), 0, stream,
                     counts, row_splits);
}

// Round 2
// 90.062 us; speedup vs baseline: 1.0175x; 1.0175x over previous
//
#include <hip/hip_runtime.h>

#define BATCH 8
#define NPTS 9225
#define MQ 4096
#define CAP 64
#define GRID 64
#define NCELLS (GRID * GRID)   // 4096; window = cx±2, cy±2 (5x5 cells)
#define TOTPTS (BATCH * NPTS)  // 73800
// coverage margin: query at qx covers [ (cx-2)/64, (cx+3)/64 ) => >= 2/64 =
// 0.03125 each side vs r = 0.03 (+fp32-expansion slack ~2e-6).

__device__ __forceinline__ int cell_of(float x, float y) {
  int cx = (int)(x * (float)GRID);
  int cy = (int)(y * (float)GRID);
  cx = min(max(cx, 0), GRID - 1);
  cy = min(max(cy, 0), GRID - 1);
  return cy * GRID + cx;
}

// ---- build stage: wide global-atomic hist + wide scatter (R6); scan stays
// at 8 blocks (cheap). ----

__global__ __launch_bounds__(1024) void zero_hist_kernel(int* __restrict__ hist) {
  hist[blockIdx.x * 1024 + threadIdx.x] = 0;  // grid sized exactly: 32*1024
}

__global__ __launch_bounds__(256) void hist_kernel(
    const float* __restrict__ data, int* __restrict__ hist) {
  const int f = blockIdx.x * 256 + threadIdx.x;
  if (f >= TOTPTS) return;
  const float2 p = ((const float2*)data)[f];
  const unsigned b = (unsigned)f / (unsigned)NPTS;  // magic-mul
  atomicAdd(&hist[b * NCELLS + cell_of(p.x, p.y)], 1);
}

// Per-batch exclusive scan of 4096 cell counts; writes cell_starts + cursor.
__global__ __launch_bounds__(1024) void scan_cells_kernel(
    const int* __restrict__ hist,
    int* __restrict__ cell_starts,   // [B][NCELLS+1]
    int* __restrict__ cursor) {      // [B][NCELLS]
  __shared__ int wavesum[16];
  const int b = blockIdx.x;
  const int t = threadIdx.x;
  const int* h = hist + b * NCELLS;
  const int c0 = h[4 * t + 0], c1 = h[4 * t + 1];
  const int c2 = h[4 * t + 2], c3 = h[4 * t + 3];
  const int s = c0 + c1 + c2 + c3;
  const int lane = t & 63, wid = t >> 6;
  int v = s;
#pragma unroll
  for (int off = 1; off < 64; off <<= 1) {
    const int u = __shfl_up(v, off, 64);
    if (lane >= off) v += u;
  }
  if (lane == 63) wavesum[wid] = v;
  __syncthreads();
  int woff = 0;
  for (int k = 0; k < wid; ++k) woff += wavesum[k];
  int e = woff + v - s;  // exclusive prefix of cell 4t
  int* cs = cell_starts + b * (NCELLS + 1);
  int* cu = cursor + b * NCELLS;
  cs[4 * t + 0] = e; cu[4 * t + 0] = e; e += c0;
  cs[4 * t + 1] = e; cu[4 * t + 1] = e; e += c1;
  cs[4 * t + 2] = e; cu[4 * t + 2] = e; e += c2;
  cs[4 * t + 3] = e; cu[4 * t + 3] = e; e += c3;
  if (t == 1023) cs[NCELLS] = e;  // == NPTS
}

__global__ __launch_bounds__(256) void scatter_kernel(
    const float* __restrict__ data, int* __restrict__ cursor,
    float4* __restrict__ recs) {
  const int f = blockIdx.x * 256 + threadIdx.x;
  if (f >= TOTPTS) return;
  const float2 p = ((const float2*)data)[f];
  const unsigned b = (unsigned)f / (unsigned)NPTS;
  const int i = f - (int)b * NPTS;  // index within batch
  const int pos = atomicAdd(&cursor[b * NCELLS + cell_of(p.x, p.y)], 1);
  recs[(size_t)b * NPTS + pos] = make_float4(p.x, p.y, __int_as_float(i), 0.0f);
}

// One wave per query; 5 cell-rows concatenated into one lane-mapped stream.
// R7: row-window setup rewritten as a STATIC 5-iteration unroll. The old
// `rstart[nr++]` runtime-indexed writes forced rstart/rlen into scratch
// (LLVM can't SROA runtime-indexed locals) -> 10 scratch stores + 5 scratch
// loads on every wave's critical path. Static indices -> pure registers.
__global__ __launch_bounds__(256) void search_kernel(
    const float* __restrict__ queries, const float* __restrict__ radius_p,
    const int* __restrict__ cell_starts, const float4* __restrict__ recs,
    int* __restrict__ nbr_idx, int* __restrict__ counts) {
#pragma clang fp contract(off)
  __shared__ int hitbuf[4][CAP];
  const int lane = threadIdx.x & 63;
  const int w = threadIdx.x >> 6;
  const int q = blockIdx.x * 4 + w;     // grid sized exactly
  const int b = q >> 12;                // MQ = 4096
  const float r = radius_p[0];
  const float r2 = r * r;
  const float2 qv = ((const float2*)queries)[q];
  const float qx = qv.x, qy = qv.y;
  const float qn = qx * qx + qy * qy;   // mul,mul,add — no fma (matches np)

  const int cx = min(max((int)(qx * (float)GRID), 0), GRID - 1);
  const int cy = min(max((int)(qy * (float)GRID), 0), GRID - 1);
  const int x0 = max(cx - 2, 0), x1 = min(cx + 2, GRID - 1);

  const int csbase = b * (NCELLS + 1);
  int rstart[5], rlen[5];
#pragma unroll
  for (int k = 0; k < 5; ++k) {         // static indices -> registers
    const int y = cy + (k - 2);
    const bool ok = (y >= 0) && (y <= GRID - 1);
    const int yy = min(max(y, 0), GRID - 1);   // safe address when !ok
    const int s0 = cell_starts[csbase + yy * GRID + x0];
    const int s1 = cell_starts[csbase + yy * GRID + x1 + 1];
    rstart[k] = s0;
    rlen[k] = ok ? (s1 - s0) : 0;
  }
  const int L0 = rlen[0];
  const int L1 = L0 + rlen[1];
  const int L2 = L1 + rlen[2];
  const int L3 = L2 + rlen[3];
  const int T = L3 + rlen[4];

  const unsigned long long below = (1ull << lane) - 1ull;
  const float4* rb = recs + (size_t)b * NPTS;
  int h = 0;

  for (int base = 0; base < T; base += 64) {
    const int p = base + lane;
    const bool act = (p < T);
    int i;
    if (p < L0)      i = rstart[0] + p;
    else if (p < L1) i = rstart[1] + (p - L0);
    else if (p < L2) i = rstart[2] + (p - L1);
    else if (p < L3) i = rstart[3] + (p - L2);
    else             i = rstart[4] + (p - L3);
    if (!act) i = 0;  // safe address
    const float4 rec = rb[i];
    const float dx = rec.x, dy = rec.y;
    const int id = __float_as_int(rec.z);
    const float dn = dx * dx + dy * dy;            // mul,mul,add — no fma
    const float cross = qx * dx + qy * dy;         // mul,mul,add — no fma
    const float s = (qn + dn) - 2.0f * cross;      // matches np op order
    const bool in = act && (s <= r2);
    const unsigned long long mask = __ballot(in);
    if (in) {
      const int pos = h + __popcll(mask & below);
      if (pos < CAP) hitbuf[w][pos] = id;
    }
    h += __popcll(mask);
  }

  // gather (same-wave LDS RAW is in-order)
  int v = (lane < h && lane < CAP) ? hitbuf[w][lane] : 0x7fffffff;

  // bitonic sort: k=2..32 sorts each 32-half (high half = all-MAX)
#pragma unroll
  for (int k = 2; k <= 32; k <<= 1) {
#pragma unroll
    for (int j = k >> 1; j >= 1; j >>= 1) {
      const int other = __shfl_xor(v, j, 64);
      const bool keep_min = (((lane & k) == 0) == ((lane & j) == 0));
      v = keep_min ? min(v, other) : max(v, other);
    }
  }
  if (h > 32) {  // final 64-merge only if hits spill past lane 31
#pragma unroll
    for (int j = 32; j >= 1; j >>= 1) {
      const int other = __shfl_xor(v, j, 64);
      const bool keep_min = ((lane & j) == 0);
      v = keep_min ? min(v, other) : max(v, other);
    }
  }

  nbr_idx[(size_t)q * CAP + lane] = (v == 0x7fffffff) ? -1 : v;
  if (lane == 0) counts[q] = h;
}

// Per-batch exclusive scan of 4096 counts -> row_splits[b][0..4096]
__global__ __launch_bounds__(256) void scan_kernel(const int* __restrict__ counts,
                                                   int* __restrict__ row_splits) {
  const int b = blockIdx.x;
  const int t = threadIdx.x;
  const int PER = MQ / 256;  // 16
  __shared__ int partial[256];
  const int* c = counts + b * MQ;
  int local[PER];
  int sum = 0;
#pragma unroll
  for (int k = 0; k < PER; ++k) { local[k] = c[t * PER + k]; sum += local[k]; }
  partial[t] = sum;
  __syncthreads();
  for (int off = 1; off < 256; off <<= 1) {
    int u = (t >= off) ? partial[t - off] : 0;
    __syncthreads();
    partial[t] += u;
    __syncthreads();
  }
  const int excl = (t == 0) ? 0 : partial[t - 1];
  int* rs = row_splits + b * (MQ + 1);
  if (t == 0) rs[0] = 0;
  int run = excl;
#pragma unroll
  for (int k = 0; k < PER; ++k) { run += local[k]; rs[t * PER + k + 1] = run; }
}

extern "C" void kernel_launch(void* const* d_in, const int* in_sizes, int n_in,
                              void* d_out, int out_size, void* d_ws, size_t ws_size,
                              hipStream_t stream) {
  const float* data    = (const float*)d_in[0];
  const float* queries = (const float*)d_in[1];
  const float* radius  = (const float*)d_in[2];
  int* out        = (int*)d_out;
  int* nbr_idx    = out;                       // BATCH*MQ*CAP
  int* row_splits = out + BATCH * MQ * CAP;    // BATCH*(MQ+1)

  // workspace layout (ints): counts[32768] + cell_starts[8*4097=32776] +
  // hist[32768] + cursor[32768] = 131080 ints = 524320 B, divisible by 16
  // -> recs is 16B-aligned.
  int* counts      = (int*)d_ws;                           // 32768
  int* cell_starts = counts + BATCH * MQ;                  // 32776
  int* hist        = cell_starts + BATCH * (NCELLS + 1);   // 32768
  int* cursor      = hist + BATCH * NCELLS;                // 32768
  float4* recs     = (float4*)(cursor + BATCH * NCELLS);

  const int PT_BLOCKS = (TOTPTS + 255) / 256;  // 289

  hipLaunchKernelGGL(zero_hist_kernel, dim3(BATCH * NCELLS / 1024), dim3(1024),
                     0, stream, hist);
  hipLaunchKernelGGL(hist_kernel, dim3(PT_BLOCKS), dim3(256), 0, stream,
                     data, hist);
  hipLaunchKernelGGL(scan_cells_kernel, dim3(BATCH), dim3(1024), 0, stream,
                     hist, cell_starts, cursor);
  hipLaunchKernelGGL(scatter_kernel, dim3(PT_BLOCKS), dim3(256), 0, stream,
                     data, cursor, recs);
  hipLaunchKernelGGL(search_kernel, dim3(BATCH * MQ / 4), dim3(256), 0, stream,
                     queries, radius, cell_starts, recs, nbr_idx, counts);
  hipLaunchKernelGGL(scan_kernel, dim3(BATCH), dim3(256), 0, stream,
                     counts, row_splits);
}

// Round 3
// 88.449 us; speedup vs baseline: 1.0360x; 1.0182x over previous
//
#include <hip/hip_runtime.h>

#define BATCH 8
#define NPTS 9225
#define MQ 4096
#define CAP 64
#define GRID 64
#define NCELLS (GRID * GRID)   // 4096; window = cx±2, cy±2 (5x5 cells)
// coverage margin: query at qx covers [ (cx-2)/64, (cx+3)/64 ) => >= 2/64 =
// 0.03125 each side vs r = 0.03 (+fp32-expansion slack ~2e-6).

__device__ __forceinline__ int cell_of(float x, float y) {
  int cx = (int)(x * (float)GRID);
  int cy = (int)(y * (float)GRID);
  cx = min(max(cx, 0), GRID - 1);
  cy = min(max(cy, 0), GRID - 1);
  return cy * GRID + cx;
}

// R8: back to the single-dispatch fused build (R0 version). R1 proved the
// wide 4-kernel build is perf-neutral (±0.5 µs) — the timed region is
// dominated by harness poison fills — so minimize dispatch count instead.
// One block per batch: LDS histogram -> shfl scan -> scatter.
__global__ __launch_bounds__(1024) void build_kernel(
    const float* __restrict__ data,
    int* __restrict__ cell_starts,   // [B][NCELLS+1]
    float4* __restrict__ recs) {     // [B][NPTS]
  __shared__ int hist[NCELLS];
  __shared__ int cursor[NCELLS];
  __shared__ int wavesum[16];
  const int b = blockIdx.x;
  const int t = threadIdx.x;
#pragma unroll
  for (int k = 0; k < NCELLS / 1024; ++k) hist[t + k * 1024] = 0;
  __syncthreads();

  const float2* dp = (const float2*)data + (size_t)b * NPTS;
  for (int i = t; i < NPTS; i += 1024)
    atomicAdd(&hist[cell_of(dp[i].x, dp[i].y)], 1);
  __syncthreads();

  // scan: thread t owns cells [4t, 4t+4)
  const int c0 = hist[4 * t + 0], c1 = hist[4 * t + 1];
  const int c2 = hist[4 * t + 2], c3 = hist[4 * t + 3];
  const int s = c0 + c1 + c2 + c3;
  const int lane = t & 63, wid = t >> 6;
  int v = s;
#pragma unroll
  for (int off = 1; off < 64; off <<= 1) {
    const int u = __shfl_up(v, off, 64);
    if (lane >= off) v += u;
  }
  if (lane == 63) wavesum[wid] = v;
  __syncthreads();
  int woff = 0;
  for (int k = 0; k < wid; ++k) woff += wavesum[k];
  int e = woff + v - s;  // exclusive prefix of cell 4t
  int* cs = cell_starts + b * (NCELLS + 1);
  cs[4 * t + 0] = e; cursor[4 * t + 0] = e; e += c0;
  cs[4 * t + 1] = e; cursor[4 * t + 1] = e; e += c1;
  cs[4 * t + 2] = e; cursor[4 * t + 2] = e; e += c2;
  cs[4 * t + 3] = e; cursor[4 * t + 3] = e; e += c3;
  if (t == 1023) cs[NCELLS] = e;  // == NPTS
  __syncthreads();

  float4* rb = recs + (size_t)b * NPTS;
  for (int i = t; i < NPTS; i += 1024) {
    const float2 p = dp[i];  // re-read (L2 hit)
    const int pos = atomicAdd(&cursor[cell_of(p.x, p.y)], 1);
    rb[pos] = make_float4(p.x, p.y, __int_as_float(i), 0.0f);
  }
}

// One wave per query; 5 cell-rows concatenated into one lane-mapped stream.
// R7: row-window setup is a STATIC 5-iteration unroll (runtime-indexed
// rstart[nr++] forced scratch allocation; static indices -> registers).
__global__ __launch_bounds__(256) void search_kernel(
    const float* __restrict__ queries, const float* __restrict__ radius_p,
    const int* __restrict__ cell_starts, const float4* __restrict__ recs,
    int* __restrict__ nbr_idx, int* __restrict__ counts) {
#pragma clang fp contract(off)
  __shared__ int hitbuf[4][CAP];
  const int lane = threadIdx.x & 63;
  const int w = threadIdx.x >> 6;
  const int q = blockIdx.x * 4 + w;     // grid sized exactly
  const int b = q >> 12;                // MQ = 4096
  const float r = radius_p[0];
  const float r2 = r * r;
  const float2 qv = ((const float2*)queries)[q];
  const float qx = qv.x, qy = qv.y;
  const float qn = qx * qx + qy * qy;   // mul,mul,add — no fma (matches np)

  const int cx = min(max((int)(qx * (float)GRID), 0), GRID - 1);
  const int cy = min(max((int)(qy * (float)GRID), 0), GRID - 1);
  const int x0 = max(cx - 2, 0), x1 = min(cx + 2, GRID - 1);

  const int csbase = b * (NCELLS + 1);
  int rstart[5], rlen[5];
#pragma unroll
  for (int k = 0; k < 5; ++k) {         // static indices -> registers
    const int y = cy + (k - 2);
    const bool ok = (y >= 0) && (y <= GRID - 1);
    const int yy = min(max(y, 0), GRID - 1);   // safe address when !ok
    const int s0 = cell_starts[csbase + yy * GRID + x0];
    const int s1 = cell_starts[csbase + yy * GRID + x1 + 1];
    rstart[k] = s0;
    rlen[k] = ok ? (s1 - s0) : 0;
  }
  const int L0 = rlen[0];
  const int L1 = L0 + rlen[1];
  const int L2 = L1 + rlen[2];
  const int L3 = L2 + rlen[3];
  const int T = L3 + rlen[4];

  const unsigned long long below = (1ull << lane) - 1ull;
  const float4* rb = recs + (size_t)b * NPTS;
  int h = 0;

  for (int base = 0; base < T; base += 64) {
    const int p = base + lane;
    const bool act = (p < T);
    int i;
    if (p < L0)      i = rstart[0] + p;
    else if (p < L1) i = rstart[1] + (p - L0);
    else if (p < L2) i = rstart[2] + (p - L1);
    else if (p < L3) i = rstart[3] + (p - L2);
    else             i = rstart[4] + (p - L3);
    if (!act) i = 0;  // safe address
    const float4 rec = rb[i];
    const float dx = rec.x, dy = rec.y;
    const int id = __float_as_int(rec.z);
    const float dn = dx * dx + dy * dy;            // mul,mul,add — no fma
    const float cross = qx * dx + qy * dy;         // mul,mul,add — no fma
    const float s = (qn + dn) - 2.0f * cross;      // matches np op order
    const bool in = act && (s <= r2);
    const unsigned long long mask = __ballot(in);
    if (in) {
      const int pos = h + __popcll(mask & below);
      if (pos < CAP) hitbuf[w][pos] = id;
    }
    h += __popcll(mask);
  }

  // gather (same-wave LDS RAW is in-order)
  int v = (lane < h && lane < CAP) ? hitbuf[w][lane] : 0x7fffffff;

  // bitonic sort: k=2..32 sorts each 32-half (high half = all-MAX)
#pragma unroll
  for (int k = 2; k <= 32; k <<= 1) {
#pragma unroll
    for (int j = k >> 1; j >= 1; j >>= 1) {
      const int other = __shfl_xor(v, j, 64);
      const bool keep_min = (((lane & k) == 0) == ((lane & j) == 0));
      v = keep_min ? min(v, other) : max(v, other);
    }
  }
  if (h > 32) {  // final 64-merge only if hits spill past lane 31
#pragma unroll
    for (int j = 32; j >= 1; j >>= 1) {
      const int other = __shfl_xor(v, j, 64);
      const bool keep_min = ((lane & j) == 0);
      v = keep_min ? min(v, other) : max(v, other);
    }
  }

  nbr_idx[(size_t)q * CAP + lane] = (v == 0x7fffffff) ? -1 : v;
  if (lane == 0) counts[q] = h;
}

// Per-batch exclusive scan of 4096 counts -> row_splits[b][0..4096]
__global__ __launch_bounds__(256) void scan_kernel(const int* __restrict__ counts,
                                                   int* __restrict__ row_splits) {
  const int b = blockIdx.x;
  const int t = threadIdx.x;
  const int PER = MQ / 256;  // 16
  __shared__ int partial[256];
  const int* c = counts + b * MQ;
  int local[PER];
  int sum = 0;
#pragma unroll
  for (int k = 0; k < PER; ++k) { local[k] = c[t * PER + k]; sum += local[k]; }
  partial[t] = sum;
  __syncthreads();
  for (int off = 1; off < 256; off <<= 1) {
    int u = (t >= off) ? partial[t - off] : 0;
    __syncthreads();
    partial[t] += u;
    __syncthreads();
  }
  const int excl = (t == 0) ? 0 : partial[t - 1];
  int* rs = row_splits + b * (MQ + 1);
  if (t == 0) rs[0] = 0;
  int run = excl;
#pragma unroll
  for (int k = 0; k < PER; ++k) { run += local[k]; rs[t * PER + k + 1] = run; }
}

extern "C" void kernel_launch(void* const* d_in, const int* in_sizes, int n_in,
                              void* d_out, int out_size, void* d_ws, size_t ws_size,
                              hipStream_t stream) {
  const float* data    = (const float*)d_in[0];
  const float* queries = (const float*)d_in[1];
  const float* radius  = (const float*)d_in[2];
  int* out        = (int*)d_out;
  int* nbr_idx    = out;                       // BATCH*MQ*CAP
  int* row_splits = out + BATCH * MQ * CAP;    // BATCH*(MQ+1)

  // workspace layout (ints); counts+cell_starts = 65544 ints = 262176 B,
  // divisible by 16 -> recs is 16B-aligned.
  int* counts      = (int*)d_ws;                         // 32768
  int* cell_starts = counts + BATCH * MQ;                // 8*4097 = 32776
  float4* recs     = (float4*)(cell_starts + BATCH * (NCELLS + 1));

  hipLaunchKernelGGL(build_kernel, dim3(BATCH), dim3(1024), 0, stream,
                     data, cell_starts, recs);
  hipLaunchKernelGGL(search_kernel, dim3(BATCH * MQ / 4), dim3(256), 0, stream,
                     queries, radius, cell_starts, recs, nbr_idx, counts);
  hipLaunchKernelGGL(scan_kernel, dim3(BATCH), dim3(256), 0, stream,
                     counts, row_splits);
}